// Round 13
// baseline (275.706 us; speedup 1.0000x reference)
//
#include <hip/hip_runtime.h>

#define TAU_INV 2.0f
#define R_ 5
#define NU 50000
#define NM 20000
#define EDGES 100000
#define F_ 4
#define D_ 16
#define DR 64
#define OUT_ 64
#define EPW 16  // edges per wave in k_edge_msg

__device__ __forceinline__ float dot4(float4 a, float4 b) {
    return a.x * b.x + a.y * b.y + a.z * b.z + a.w * b.w;
}

// 4 edges per wave, 16 lanes per edge. ~4 shfl/edge, float4 loads.
__global__ __launch_bounds__(256) void k_edge_w(
    const float* __restrict__ ufk, const float* __restrict__ mfk,
    const float* __restrict__ ufs, const float* __restrict__ mfs,
    const float* __restrict__ rfeat, const float* __restrict__ proto,
    const float* __restrict__ eta, const int* __restrict__ eu,
    const int* __restrict__ em, const int* __restrict__ kp,
    float* __restrict__ wbuf, float* __restrict__ nrm_u, float* __restrict__ nrm_m)
{
    const int tid = threadIdx.x;
    const int wv = tid >> 6, l = tid & 63;
    const int g16 = l >> 4;          // edge slot within wave
    const int j   = l & 15;          // lane within 16-lane group
    const int r = blockIdx.y;
    int e = (blockIdx.x * 4 + wv) * 4 + g16;
    const bool live = (e < EDGES);
    if (e >= EDGES) e = EDGES - 1;
    const int idx = r * EDGES + e;
    const int u = eu[idx], m = em[idx];
    const int kk = kp[0];

    // ---- sim_all: 64 floats; lane j dots float4 #j; f = j>>2 ----
    const float4 pu = ((const float4*)(ufs + (size_t)(r * NU + u) * 64))[j];
    const float4 pm = ((const float4*)(mfs + (size_t)(r * NM + m) * 64))[j];
    float p = dot4(pu, pm);
    p += __shfl_xor(p, 1); p += __shfl_xor(p, 2);      // per-f dot at subgroup
    const float es = expf(p * TAU_INV);
    float dsim = es;
    dsim += __shfl_xor(dsim, 4); dsim += __shfl_xor(dsim, 8);  // sum over f, all lanes

    // ---- sim_k: 16 floats; lanes use jc=j&3 ----
    const int jc = j & 3;
    const float4 u4 = ((const float4*)(ufk + (size_t)(r * NU + u) * 16))[jc];
    const float4 m4 = ((const float4*)(mfk + (size_t)(r * NM + m) * 16))[jc];
    float su = dot4(u4, u4), sm = dot4(m4, m4), sd = dot4(u4, m4);
    su += __shfl_xor(su, 1); su += __shfl_xor(su, 2);
    sm += __shfl_xor(sm, 1); sm += __shfl_xor(sm, 2);
    sd += __shfl_xor(sd, 1); sd += __shfl_xor(sd, 2);
    const float nsim = expf(sd / (fmaxf(sqrtf(su), 1e-12f) * fmaxf(sqrtf(sm), 1e-12f)) * TAU_INV);

    // ---- anchor: 256 floats; lane j handles f=j>>2, chunk c=j&3 ----
    const float4* rf4 = (const float4*)(rfeat + (size_t)idx * 256);
    const float4* pr4 = (const float4*)proto;
    const int base = (j >> 2) * 16 + (j & 3) * 4;
    float ap = 0.f;
#pragma unroll
    for (int t = 0; t < 4; ++t)
        ap += dot4(rf4[base + t], pr4[base + t]);
    ap += __shfl_xor(ap, 1); ap += __shfl_xor(ap, 2);  // f-dot at subgroup
    const float ea = expf(ap * TAU_INV);
    float dan = ea;
    dan += __shfl_xor(dan, 4); dan += __shfl_xor(dan, 8);
    const float adk = __shfl(ap, (l & 48) | (kk << 2)); // ad_all[k] (full convergence)
    const float na = expf(adk * TAU_INV);

    const float gt = 1.0f / (1.0f + expf(-eta[idx]));
    const float w = gt * (na / dan) + (1.0f - gt) * (nsim / dsim);

    if (live && j == 0) {
        wbuf[idx] = w;
        atomicAdd(&nrm_u[u], w);
        atomicAdd(&nrm_m[m], w);
    }
}

// One wave per EPW=16 edges. LDS-DIET: only rf_k staged in LDS (16 f4/edge,
// pow2 addressing, no staging shuffles); ufk/mfk quarters read DIRECT from
// global (16-lane same-address broadcast, L2-resident tables). Atomics paired
// (2 edges per 64-lane instr). All __shfl at full wave convergence.
__global__ __launch_bounds__(256) void k_edge_msg(
    const float* __restrict__ ufk, const float* __restrict__ mfk,
    const float* __restrict__ rfeat,
    const float* __restrict__ nwf, const float* __restrict__ rwf,
    const float* __restrict__ nwr, const float* __restrict__ rwr,
    const int* __restrict__ eu, const int* __restrict__ em, const int* __restrict__ kp,
    const float* __restrict__ wbuf, const float* __restrict__ nrm_u,
    const float* __restrict__ nrm_m,
    float* __restrict__ upre, float* __restrict__ ipre, float* __restrict__ dist_out)
{
    __shared__ __align__(16) float4 lds[4][EPW * 16]; // 16 KB: per wave, 16 edges x 16 float4 (rf only)

    const int tid = threadIdx.x;
    const int wv = tid >> 6, l = tid & 63;
    const int o = l & 15, q = l >> 4;
    const int r = blockIdx.y;
    const int kk = kp[0];
    const int rE = r * EDGES;

    const float4* pwf = (const float4*)(rwf + (size_t)r * 1024 + o * 64 + q * 16);
    const float4* pwr = (const float4*)(rwr + (size_t)r * 1024 + o * 64 + q * 16);
    const float4 wf0 = pwf[0], wf1 = pwf[1], wf2 = pwf[2], wf3 = pwf[3];
    const float4 wr0 = pwr[0], wr1 = pwr[1], wr2 = pwr[2], wr3 = pwr[3];
    const float4 nf = *(const float4*)(nwf + r * 256 + o * 16 + q * 4);
    const float4 nr = *(const float4*)(nwr + r * 256 + o * 16 + q * 4);

    const int ebase = (blockIdx.x * 4 + wv) * EPW;

    // header: lane group (l&15)=j holds edge ebase+j's ids / weight / norms
    int eu16, em16; float wn16;
    {
        int e2 = ebase + (l & 15); if (e2 >= EDGES) e2 = EDGES - 1;
        eu16 = eu[rE + e2]; em16 = em[rE + e2];
        const float w0 = wbuf[rE + e2];
        wn16 = w0 / sqrtf(nrm_u[eu16] * nrm_m[em16]);
    }

    if (l < EPW && ebase + l < EDGES)
        dist_out[rE + ebase + l] = wn16;

    // ---- stage rf_k for all 16 edges: 256 float4 slots; lane l owns l+64t ----
    float4 st[4];
#pragma unroll
    for (int t = 0; t < 4; ++t) {
        const int s = l + 64 * t;
        const int j = s >> 4;            // edge 0..15
        const int p = s & 15;            // float4 index within rf row
        int e2 = ebase + j; if (e2 >= EDGES) e2 = EDGES - 1;
        st[t] = ((const float4*)(rfeat + ((size_t)(rE + e2) * 4 + kk) * 64))[p];
    }
#pragma unroll
    for (int t = 0; t < 4; ++t)
        lds[wv][l + 64 * t] = st[t];

    // ---- compute 16 edges, 2 at a time; one 64-lane atomic per PAIR ----
#pragma unroll
    for (int j = 0; j < EPW; j += 2) {
        // all shuffles at full convergence, hoisted to iteration top
        const int u0 = __shfl(eu16, j),     m0 = __shfl(em16, j);
        const int u1 = __shfl(eu16, j + 1), m1 = __shfl(em16, j + 1);
        const float wnA = __shfl(wn16, j);
        const float wnB = __shfl(wn16, j + 1);

        // node feats direct from global: 16-lane same-address broadcast (L2-hot)
        const float4 uf0 = ((const float4*)(ufk + (size_t)(r * NU + u0) * 16))[q];
        const float4 mf0 = ((const float4*)(mfk + (size_t)(r * NM + m0) * 16))[q];
        const float4 uf1 = ((const float4*)(ufk + (size_t)(r * NU + u1) * 16))[q];
        const float4 mf1 = ((const float4*)(mfk + (size_t)(r * NM + m1) * 16))[q];

        float amv[2], auv[2];
        {
            const float4* L = &lds[wv][j * 16 + q * 4];
            float am = dot4(L[0], wf0) + dot4(L[1], wf1) + dot4(L[2], wf2) + dot4(L[3], wf3)
                     + dot4(uf0, nf);
            float au = dot4(L[0], wr0) + dot4(L[1], wr1) + dot4(L[2], wr2) + dot4(L[3], wr3)
                     + dot4(mf0, nr);
            am += __shfl_xor(am, 16); am += __shfl_xor(am, 32);
            au += __shfl_xor(au, 16); au += __shfl_xor(au, 32);
            amv[0] = am * wnA; auv[0] = au * wnA;
        }
        {
            const float4* L = &lds[wv][(j + 1) * 16 + q * 4];
            float am = dot4(L[0], wf0) + dot4(L[1], wf1) + dot4(L[2], wf2) + dot4(L[3], wf3)
                     + dot4(uf1, nf);
            float au = dot4(L[0], wr0) + dot4(L[1], wr1) + dot4(L[2], wr2) + dot4(L[3], wr3)
                     + dot4(mf1, nr);
            am += __shfl_xor(am, 16); am += __shfl_xor(am, 32);
            au += __shfl_xor(au, 16); au += __shfl_xor(au, 32);
            amv[1] = am * wnB; auv[1] = au * wnB;
        }

        const int  half = l >> 5;             // 0: edge j, 1: edge j+1
        const bool liveA = (ebase + j + half) < EDGES;
        float  val;
        float* base;
        if (half == 0) {
            val  = (l < 16) ? amv[0] : auv[0];
            base = (l < 16) ? &ipre[(size_t)m0 * 16 + o] : &upre[(size_t)u0 * 16 + o];
        } else {
            val  = (l < 48) ? amv[1] : auv[1];
            base = (l < 48) ? &ipre[(size_t)m1 * 16 + o] : &upre[(size_t)u1 * 16 + o];
        }
        if (liveA) atomicAdd(base, val);
    }
}

// Fused leaky-relu + (N,16) x (16,64) FC for both tables.
__global__ __launch_bounds__(256) void k_fc(
    const float* __restrict__ upre, const float* __restrict__ ipre,
    const float* __restrict__ uw, const float* __restrict__ ub,
    const float* __restrict__ iw, const float* __restrict__ ib,
    float* __restrict__ out_u, float* __restrict__ out_i)
{
    const int tid = threadIdx.x;
    const int n = blockIdx.x * 4 + (tid >> 6);
    if (n >= NU + NM) return;
    const int o = tid & 63;
    const float* pre; const float* W; const float* B; float* dst;
    if (n < NU) { pre = upre + (size_t)n * 16; W = uw; B = ub; dst = out_u + (size_t)n * 64; }
    else { int n2 = n - NU; pre = ipre + (size_t)n2 * 16; W = iw; B = ib; dst = out_i + (size_t)n2 * 64; }
    float acc = B[o];
#pragma unroll
    for (int d = 0; d < 16; d++) {
        float x = pre[d];
        x = x >= 0.f ? x : 0.1f * x;
        acc += x * W[o * 16 + d];
    }
    dst[o] = acc;
}

extern "C" void kernel_launch(void* const* d_in, const int* in_sizes, int n_in,
                              void* d_out, int out_size, void* d_ws, size_t ws_size,
                              hipStream_t stream) {
    const float* ufk  = (const float*)d_in[0];
    const float* mfk  = (const float*)d_in[1];
    const float* ufs  = (const float*)d_in[2];
    const float* mfs  = (const float*)d_in[3];
    const float* rfe  = (const float*)d_in[4];
    const float* pro  = (const float*)d_in[5];
    const float* eta  = (const float*)d_in[6];
    const float* nwf  = (const float*)d_in[7];
    const float* rwf  = (const float*)d_in[8];
    const float* nwr  = (const float*)d_in[9];
    const float* rwr  = (const float*)d_in[10];
    const float* uw   = (const float*)d_in[11];
    const float* ub   = (const float*)d_in[12];
    const float* iw   = (const float*)d_in[13];
    const float* ib   = (const float*)d_in[14];
    const int*   eu   = (const int*)d_in[15];
    const int*   em   = (const int*)d_in[16];
    const int*   kp   = (const int*)d_in[17];

    float* out    = (float*)d_out;
    float* out_u  = out;                         // NU*64
    float* out_i  = out + (size_t)NU * 64;       // NM*64
    float* out_d  = out_i + (size_t)NM * 64;     // R*E

    float* ws    = (float*)d_ws;
    float* nrm_u = ws;                           // NU
    float* nrm_m = nrm_u + NU;                   // NM
    float* upre  = nrm_m + NM;                   // NU*16
    float* ipre  = upre + (size_t)NU * 16;       // NM*16
    float* wbuf  = ipre + (size_t)NM * 16;       // R*E

    const size_t zeroN = (size_t)NU + NM + (size_t)NU * 16 + (size_t)NM * 16;
    hipMemsetAsync(d_ws, 0, zeroN * sizeof(float), stream);

    dim3 gW((EDGES + 15) / 16, R_);
    k_edge_w<<<gW, 256, 0, stream>>>(ufk, mfk, ufs, mfs, rfe, pro, eta, eu, em, kp,
                                     wbuf, nrm_u, nrm_m);
    dim3 gM((EDGES + 4 * EPW - 1) / (4 * EPW), R_);
    k_edge_msg<<<gM, 256, 0, stream>>>(ufk, mfk, rfe, nwf, rwf, nwr, rwr, eu, em, kp,
                                       wbuf, nrm_u, nrm_m, upre, ipre, out_d);
    k_fc<<<((NU + NM) + 3) / 4, 256, 0, stream>>>(upre, ipre, uw, ub, iw, ib, out_u, out_i);
}

// Round 14
// 244.211 us; speedup vs baseline: 1.1290x; 1.1290x over previous
//
#include <hip/hip_runtime.h>
#include <hip/hip_bf16.h>

#define TAU_INV 2.0f
#define R_ 5
#define NU 50000
#define NM 20000
#define EDGES 100000
#define F_ 4
#define D_ 16
#define DR 64
#define OUT_ 64
#define EPW 32  // edges per wave in k_edge_msg (2 MFMA 16-blocks)

typedef __attribute__((ext_vector_type(8))) short short8;  // 8 bf16
typedef __attribute__((ext_vector_type(4))) float f32x4;

__device__ __forceinline__ float dot4(float4 a, float4 b) {
    return a.x * b.x + a.y * b.y + a.z * b.z + a.w * b.w;
}

__device__ __forceinline__ ushort f2bf(float x) {
    __hip_bfloat16 h = __float2bfloat16(x);
    return *reinterpret_cast<ushort*>(&h);
}

__device__ __forceinline__ short8 pack8(float4 lo, float4 hi) {
    short8 v;
    v[0] = (short)f2bf(lo.x); v[1] = (short)f2bf(lo.y);
    v[2] = (short)f2bf(lo.z); v[3] = (short)f2bf(lo.w);
    v[4] = (short)f2bf(hi.x); v[5] = (short)f2bf(hi.y);
    v[6] = (short)f2bf(hi.z); v[7] = (short)f2bf(hi.w);
    return v;
}

// 4 edges per wave, 16 lanes per edge. ~4 shfl/edge, float4 loads. (unchanged)
__global__ __launch_bounds__(256) void k_edge_w(
    const float* __restrict__ ufk, const float* __restrict__ mfk,
    const float* __restrict__ ufs, const float* __restrict__ mfs,
    const float* __restrict__ rfeat, const float* __restrict__ proto,
    const float* __restrict__ eta, const int* __restrict__ eu,
    const int* __restrict__ em, const int* __restrict__ kp,
    float* __restrict__ wbuf, float* __restrict__ nrm_u, float* __restrict__ nrm_m)
{
    const int tid = threadIdx.x;
    const int wv = tid >> 6, l = tid & 63;
    const int g16 = l >> 4;
    const int j   = l & 15;
    const int r = blockIdx.y;
    int e = (blockIdx.x * 4 + wv) * 4 + g16;
    const bool live = (e < EDGES);
    if (e >= EDGES) e = EDGES - 1;
    const int idx = r * EDGES + e;
    const int u = eu[idx], m = em[idx];
    const int kk = kp[0];

    const float4 pu = ((const float4*)(ufs + (size_t)(r * NU + u) * 64))[j];
    const float4 pm = ((const float4*)(mfs + (size_t)(r * NM + m) * 64))[j];
    float p = dot4(pu, pm);
    p += __shfl_xor(p, 1); p += __shfl_xor(p, 2);
    const float es = expf(p * TAU_INV);
    float dsim = es;
    dsim += __shfl_xor(dsim, 4); dsim += __shfl_xor(dsim, 8);

    const int jc = j & 3;
    const float4 u4 = ((const float4*)(ufk + (size_t)(r * NU + u) * 16))[jc];
    const float4 m4 = ((const float4*)(mfk + (size_t)(r * NM + m) * 16))[jc];
    float su = dot4(u4, u4), sm = dot4(m4, m4), sd = dot4(u4, m4);
    su += __shfl_xor(su, 1); su += __shfl_xor(su, 2);
    sm += __shfl_xor(sm, 1); sm += __shfl_xor(sm, 2);
    sd += __shfl_xor(sd, 1); sd += __shfl_xor(sd, 2);
    const float nsim = expf(sd / (fmaxf(sqrtf(su), 1e-12f) * fmaxf(sqrtf(sm), 1e-12f)) * TAU_INV);

    const float4* rf4 = (const float4*)(rfeat + (size_t)idx * 256);
    const float4* pr4 = (const float4*)proto;
    const int base = (j >> 2) * 16 + (j & 3) * 4;
    float ap = 0.f;
#pragma unroll
    for (int t = 0; t < 4; ++t)
        ap += dot4(rf4[base + t], pr4[base + t]);
    ap += __shfl_xor(ap, 1); ap += __shfl_xor(ap, 2);
    const float ea = expf(ap * TAU_INV);
    float dan = ea;
    dan += __shfl_xor(dan, 4); dan += __shfl_xor(dan, 8);
    const float adk = __shfl(ap, (l & 48) | (kk << 2));
    const float na = expf(adk * TAU_INV);

    const float gt = 1.0f / (1.0f + expf(-eta[idx]));
    const float w = gt * (na / dan) + (1.0f - gt) * (nsim / dsim);

    if (live && j == 0) {
        wbuf[idx] = w;
        atomicAdd(&nrm_u[u], w);
        atomicAdd(&nrm_m[m], w);
    }
}

// MFMA msg kernel. Per wave: 32 edges. A = [rf(64)|ufk(16)|mfk(16)] per edge
// (bf16, staged coalesced->LDS rows of 104 bf16). B_f=[Wf;nf;0], B_r=[Wr;0;nr]
// in registers (shared A-frag between the two MFMAs). D rows=edges, cols=o
// (C layout col=lane&15, row=(lane>>4)*4+i — m89-verified). f32 accumulate,
// scale by wn, scatter via paired atomics. Wave-private LDS: no __syncthreads.
__global__ __launch_bounds__(256) void k_edge_msg(
    const float* __restrict__ ufk, const float* __restrict__ mfk,
    const float* __restrict__ rfeat,
    const float* __restrict__ nwf, const float* __restrict__ rwf,
    const float* __restrict__ nwr, const float* __restrict__ rwr,
    const int* __restrict__ eu, const int* __restrict__ em, const int* __restrict__ kp,
    const float* __restrict__ wbuf, const float* __restrict__ nrm_u,
    const float* __restrict__ nrm_m,
    float* __restrict__ upre, float* __restrict__ ipre, float* __restrict__ dist_out)
{
    __shared__ __align__(16) ushort s_a[4][EPW][104];  // 26.6 KB, rows padded 96->104

    const int tid = threadIdx.x;
    const int wv = tid >> 6, l = tid & 63;
    const int o = l & 15, q = l >> 4;
    const int r = blockIdx.y;
    const int kk = kp[0];
    const int rE = r * EDGES;

    // ---- B fragments (per lane, once): B[k][o], k = 32*sl + 8*q + {0..7} ----
    short8 Bf[3], Br[3];
    {
        const float* wfp = rwf + (size_t)r * 1024 + o * 64;  // Wf[o][k]
        const float* wrp = rwr + (size_t)r * 1024 + o * 64;
        const float* nfp = nwf + r * 256 + o * 16;
        const float* nrp = nwr + r * 256 + o * 16;
#pragma unroll
        for (int sl = 0; sl < 2; ++sl) {
            const int bk = 32 * sl + 8 * q;
            Bf[sl] = pack8(*(const float4*)(wfp + bk), *(const float4*)(wfp + bk + 4));
            Br[sl] = pack8(*(const float4*)(wrp + bk), *(const float4*)(wrp + bk + 4));
        }
        const short8 z8 = {0, 0, 0, 0, 0, 0, 0, 0};
        // slice 2: k=64..95. B_f: k64-79 = nf; B_r: k80-95 = nr.
        Bf[2] = (q < 2) ? pack8(*(const float4*)(nfp + 8 * q),
                                *(const float4*)(nfp + 8 * q + 4)) : z8;
        Br[2] = (q >= 2) ? pack8(*(const float4*)(nrp + 8 * (q - 2)),
                                 *(const float4*)(nrp + 8 * (q - 2) + 4)) : z8;
    }

    const int ebase = (blockIdx.x * 4 + wv) * EPW;

    // ---- header: lane (l&31)=j holds edge ebase+j's ids / wn ----
    int eu32, em32; float wn32;
    {
        int e2 = ebase + (l & 31); if (e2 >= EDGES) e2 = EDGES - 1;
        eu32 = eu[rE + e2]; em32 = em[rE + e2];
        const float w0 = wbuf[rE + e2];
        wn32 = w0 / sqrtf(nrm_u[eu32] * nrm_m[em32]);
    }
    if (l < 32 && ebase + l < EDGES)
        dist_out[rE + ebase + l] = wn32;

    // ---- stage A rows: 32 edges x 24 f4-slots (k = 4*p uniformly) ----
    // slot p: 0-15 rf | 16-19 ufk | 20-23 mfk; cvt f32->bf16, write 8B.
    float4 st[12];
#pragma unroll
    for (int t = 0; t < 12; ++t) {
        const int s = l + 64 * t;
        const int j = s / 24;
        const int p = s % 24;
        int e2 = ebase + j; if (e2 >= EDGES) e2 = EDGES - 1;
        const int uj = __shfl(eu32, j);   // full convergence
        const int mj = __shfl(em32, j);
        const float4* src;
        if (p < 16)      src = (const float4*)(rfeat + ((size_t)(rE + e2) * 4 + kk) * 64) + p;
        else if (p < 20) src = (const float4*)(ufk + (size_t)(r * NU + uj) * 16) + (p - 16);
        else             src = (const float4*)(mfk + (size_t)(r * NM + mj) * 16) + (p - 20);
        st[t] = *src;
    }
    char* abase = (char*)&s_a[wv][0][0];
#pragma unroll
    for (int t = 0; t < 12; ++t) {
        const int s = l + 64 * t;
        const int j = s / 24;
        const int p = s % 24;
        uint2 wds;
        wds.x = (uint)f2bf(st[t].x) | ((uint)f2bf(st[t].y) << 16);
        wds.y = (uint)f2bf(st[t].z) | ((uint)f2bf(st[t].w) << 16);
        *(uint2*)(abase + j * 208 + p * 8) = wds;
    }

    // ---- 2 MFMA blocks of 16 edges each ----
#pragma unroll
    for (int g = 0; g < 2; ++g) {
        f32x4 accm = {0.f, 0.f, 0.f, 0.f};
        f32x4 accu = {0.f, 0.f, 0.f, 0.f};
        const int row = g * 16 + o;              // A row = edge slot (lane&15)
#pragma unroll
        for (int sl = 0; sl < 3; ++sl) {
            const short8 a = *(const short8*)(abase + row * 208 + (sl * 32 + 8 * q) * 2);
            accm = __builtin_amdgcn_mfma_f32_16x16x32_bf16(a, Bf[sl], accm, 0, 0, 0);
            accu = __builtin_amdgcn_mfma_f32_16x16x32_bf16(a, Br[sl], accu, 0, 0, 0);
        }
        // D: col = l&15 (=o), row = q*4+i  -> edge j = g*16 + q*4 + i
#pragma unroll
        for (int i = 0; i < 4; ++i) {
            const int j = g * 16 + q * 4 + i;
            const float wnj = __shfl(wn32, j);   // full convergence
            const int   uj  = __shfl(eu32, j);
            const int   mj  = __shfl(em32, j);
            const bool  livej = (ebase + j) < EDGES;
            const float vm = accm[i] * wnj;
            const float vu = accu[i] * wnj;
            if (livej) {
                atomicAdd(&ipre[(size_t)mj * 16 + o], vm);
                atomicAdd(&upre[(size_t)uj * 16 + o], vu);
            }
        }
    }
}

// Fused leaky-relu + (N,16) x (16,64) FC for both tables. (unchanged)
__global__ __launch_bounds__(256) void k_fc(
    const float* __restrict__ upre, const float* __restrict__ ipre,
    const float* __restrict__ uw, const float* __restrict__ ub,
    const float* __restrict__ iw, const float* __restrict__ ib,
    float* __restrict__ out_u, float* __restrict__ out_i)
{
    const int tid = threadIdx.x;
    const int n = blockIdx.x * 4 + (tid >> 6);
    if (n >= NU + NM) return;
    const int o = tid & 63;
    const float* pre; const float* W; const float* B; float* dst;
    if (n < NU) { pre = upre + (size_t)n * 16; W = uw; B = ub; dst = out_u + (size_t)n * 64; }
    else { int n2 = n - NU; pre = ipre + (size_t)n2 * 16; W = iw; B = ib; dst = out_i + (size_t)n2 * 64; }
    float acc = B[o];
#pragma unroll
    for (int d = 0; d < 16; d++) {
        float x = pre[d];
        x = x >= 0.f ? x : 0.1f * x;
        acc += x * W[o * 16 + d];
    }
    dst[o] = acc;
}

extern "C" void kernel_launch(void* const* d_in, const int* in_sizes, int n_in,
                              void* d_out, int out_size, void* d_ws, size_t ws_size,
                              hipStream_t stream) {
    const float* ufk  = (const float*)d_in[0];
    const float* mfk  = (const float*)d_in[1];
    const float* ufs  = (const float*)d_in[2];
    const float* mfs  = (const float*)d_in[3];
    const float* rfe  = (const float*)d_in[4];
    const float* pro  = (const float*)d_in[5];
    const float* eta  = (const float*)d_in[6];
    const float* nwf  = (const float*)d_in[7];
    const float* rwf  = (const float*)d_in[8];
    const float* nwr  = (const float*)d_in[9];
    const float* rwr  = (const float*)d_in[10];
    const float* uw   = (const float*)d_in[11];
    const float* ub   = (const float*)d_in[12];
    const float* iw   = (const float*)d_in[13];
    const float* ib   = (const float*)d_in[14];
    const int*   eu   = (const int*)d_in[15];
    const int*   em   = (const int*)d_in[16];
    const int*   kp   = (const int*)d_in[17];

    float* out    = (float*)d_out;
    float* out_u  = out;                         // NU*64
    float* out_i  = out + (size_t)NU * 64;       // NM*64
    float* out_d  = out_i + (size_t)NM * 64;     // R*E

    float* ws    = (float*)d_ws;
    float* nrm_u = ws;                           // NU
    float* nrm_m = nrm_u + NU;                   // NM
    float* upre  = nrm_m + NM;                   // NU*16
    float* ipre  = upre + (size_t)NU * 16;       // NM*16
    float* wbuf  = ipre + (size_t)NM * 16;       // R*E

    const size_t zeroN = (size_t)NU + NM + (size_t)NU * 16 + (size_t)NM * 16;
    hipMemsetAsync(d_ws, 0, zeroN * sizeof(float), stream);

    dim3 gW((EDGES + 15) / 16, R_);
    k_edge_w<<<gW, 256, 0, stream>>>(ufk, mfk, ufs, mfs, rfe, pro, eta, eu, em, kp,
                                     wbuf, nrm_u, nrm_m);
    dim3 gM((EDGES + 4 * EPW - 1) / (4 * EPW), R_);
    k_edge_msg<<<gM, 256, 0, stream>>>(ufk, mfk, rfe, nwf, rwf, nwr, rwr, eu, em, kp,
                                       wbuf, nrm_u, nrm_m, upre, ipre, out_d);
    k_fc<<<((NU + NM) + 3) / 4, 256, 0, stream>>>(upre, ipre, uw, ub, iw, ib, out_u, out_i);
}